// Round 11
// baseline (2012.196 us; speedup 1.0000x reference)
//
#include <hip/hip_runtime.h>
#include <hip/hip_bf16.h>
#include <math.h>

// ---------------------------------------------------------------------------
// out = (A @ D^T) * softplus(A @ R^T + rad_b) + bias
// fp32 GEMM emulated via 2-term bf16 split (hh + hl + lh), fused dual-GEMM.
//
// R11 == R10 (never benched: acquisition timeout). Full audit passed.
// Software-pipelined phases: R9 (1535us, MfmaUtil 49%) serialized
// ds_read-drain + MFMA inside each phase (lgkmcnt(0) per phase = 870cyc
// bubble/phase). Now: phase p's MFMA uses frags loaded in p-1; phase p's
// reads (for p+1) fly under p's MFMA; wait lgkmcnt(J_own) counted, never 0.
// A-frags + first-B of tile t+1 prefetch from buf^1 during t's P3/P4.
//   staging (region-retirement + read-drain safe): A@P2top, R@P3top,
//   D@P4post. vmcnt ledger: F1=vmcnt(6)@P2post (A/R of t+1 landed before
//   P3top prefetch), F2=vmcnt(6)@P4 (D of t+1 before t+1 P2 reads).
//   Tail: t126 F1="2" F2="0"; t127 "0"/"0".
//   lgkmcnt per-phase J: P1=4, P2=4, P3=8, P4=8 (FIFO: leaves own reads,
//   drains prev phase's).
// Geometry/swizzle/epilogue IDENTICAL to R8/R9 (0 conflicts, absmax 3e-5).
// ws: A_hi 0 | A_lo 64M | R_hi 128M | R_lo 160M | D_hi 192M | D_lo 224M
//     | scale 256M
// ---------------------------------------------------------------------------

typedef __bf16 bf16x8 __attribute__((ext_vector_type(8)));
typedef float  f32x4  __attribute__((ext_vector_type(4)));
typedef unsigned short u16;
typedef u16   u16x4 __attribute__((ext_vector_type(4)));
typedef float f4    __attribute__((ext_vector_type(4)));

#define BDIM 8192
#define IDIM 4096
#define ODIM 4096
#define BM 256
#define BN 128
#define BK 32
#define NKT (IDIM/BK)   // 128

__device__ __forceinline__ u16 f2bf(float x){ __bf16 h=(__bf16)x; return __builtin_bit_cast(u16,h); }
__device__ __forceinline__ float bf2f(u16 u){ return (float)__builtin_bit_cast(__bf16,u); }

__global__ void k_scale(const float* __restrict__ raw, float* __restrict__ scale){
  int o = blockIdx.x*256 + threadIdx.x;
  if(o < ODIM){
    float x = raw[o];
    float k = (x > 20.f) ? x : log1pf(expf(x));
    scale[o] = k / (k + (float)(IDIM-1));
  }
}

__global__ void k_split(const f4* __restrict__ src, u16x4* __restrict__ hi,
                        u16x4* __restrict__ lo, int n4){
  int i = blockIdx.x*blockDim.x + threadIdx.x;
  int stride = gridDim.x*blockDim.x;
  for(; i<n4; i+=stride){
    f4 v = src[i];
    u16x4 h, l;
    #pragma unroll
    for(int j=0;j<4;++j){
      float x = v[j];
      u16 hb = f2bf(x);
      h[j] = hb;
      l[j] = f2bf(x - bf2f(hb));
    }
    hi[i]=h; lo[i]=l;
  }
}

__global__ void k_split_dir(const f4* __restrict__ src, const float* __restrict__ scale,
                            u16x4* __restrict__ hi, u16x4* __restrict__ lo, int n4){
  int i = blockIdx.x*blockDim.x + threadIdx.x;
  int stride = gridDim.x*blockDim.x;
  for(; i<n4; i+=stride){
    float s = scale[i>>10];
    f4 v = src[i];
    u16x4 h, l;
    #pragma unroll
    for(int j=0;j<4;++j){
      float x = v[j]*s;
      u16 hb = f2bf(x);
      h[j] = hb;
      l[j] = f2bf(x - bf2f(hb));
    }
    hi[i]=h; lo[i]=l;
  }
}

__device__ __forceinline__ void async16(const u16* g, u16* l){
  __builtin_amdgcn_global_load_lds((const __attribute__((address_space(1))) void*)g,
                                   (__attribute__((address_space(3))) void*)l, 16, 0, 0);
}

// LDS per buffer (u16 elems): Ah[256][32]@0, Al@8192, Rh[128][32]@16384,
// Rl@20480, Dh@24576, Dl@28672. Buffer stride 32768 elems (64 KB).
__global__ __launch_bounds__(512,2) void k_gemm(
    const u16* __restrict__ Ah, const u16* __restrict__ Al,
    const u16* __restrict__ Rh, const u16* __restrict__ Rl,
    const u16* __restrict__ Dh, const u16* __restrict__ Dl,
    const float* __restrict__ rad_b, const float* __restrict__ bias,
    float* __restrict__ out)
{
  __shared__ __align__(16) u16 smem[2*32768];   // 128 KB

  const int tid  = threadIdx.x;
  const int lane = tid & 63;
  const int wid  = tid >> 6;                    // 0..7
  const int wr = wid >> 1, wc = wid & 1;        // 4M x 2N wave grid

  // bijective XCD swizzle (1024 blocks % 8 == 0)
  const int bid = blockIdx.x;
  const int swz = (bid & 7)*128 + (bid >> 3);
  const int bm = swz >> 5;                      // 0..31  (256-row panels)
  const int bn = swz & 31;                      // 0..31  (128-col panels)

  // staging: LDS dest linear; GLOBAL fetch chunk XOR-swizzled (rule #21;
  // R2/R8/R9-verified, 0 bank conflicts).
  const int r0   = tid >> 2;                    // 0..127
  const int cxor = (r0 >> 1) & 3;
  const int c0   = ((tid & 3) ^ cxor) * 8;
  const size_t arow = (size_t)(bm*BM + r0)*IDIM + c0;
  const size_t brow = (size_t)(bn*BN + r0)*IDIM + c0;
  const u16* gAh = Ah + arow;  const u16* gAl = Al + arow;
  const u16* gRh = Rh + brow;  const u16* gRl = Rl + brow;
  const u16* gDh = Dh + brow;  const u16* gDl = Dl + brow;
  u16* dst = smem + tid*8;

  // fragment reads (verified): XOR term = per-lane ((lane&15)>>1)&3
  const int lr   = lane & 15;
  const int koff = (((lane >> 4) ^ ((lr >> 1) & 3))) * 8;
  const int aoff = (wr*64 + lr)*BK + koff;
  const int boff = (wc*64 + lr)*BK + koff;

  f32x4 accR[4][4] = {};
  f32x4 accD[4][4] = {};

  // pipelined fragment registers: two A-sets (overlapping liveness),
  // ONE shared rb set (dead after P1 MFMA, reloaded at P4top)
  bf16x8 xah[4], xal[4], yah[4], yal[4], rbh[2], rbl[2];

#define MFMA16(A,B,C) __builtin_amdgcn_mfma_f32_16x16x32_bf16(A,B,C,0,0,0)

#define STAGE_FULL(BUF, KT) { \
    const int _k = (KT)*BK; \
    u16* _df = dst + (BUF)*32768; \
    async16(gAh + _k,            _df);         \
    async16(gAh + 128*IDIM + _k, _df + 4096);  \
    async16(gAl + _k,            _df + 8192);  \
    async16(gAl + 128*IDIM + _k, _df + 12288); \
    async16(gRh + _k,            _df + 16384); \
    async16(gRl + _k,            _df + 20480); \
    async16(gDh + _k,            _df + 24576); \
    async16(gDl + _k,            _df + 28672); \
  }

// counted lgkm: leaves own (just-issued) J reads in flight, drains prev phase
#define PH_PRE(J) \
    __builtin_amdgcn_sched_barrier(0); \
    __builtin_amdgcn_s_barrier(); \
    asm volatile("s_waitcnt lgkmcnt(" J ")" ::: "memory"); \
    __builtin_amdgcn_sched_barrier(0); \
    __builtin_amdgcn_s_setprio(1);
#define PH_POST \
    __builtin_amdgcn_s_setprio(0); \
    __builtin_amdgcn_s_barrier(); \
    __builtin_amdgcn_sched_barrier(0);
#define PH_POST_VM(VM) \
    __builtin_amdgcn_s_setprio(0); \
    asm volatile("s_waitcnt vmcnt(" VM ")" ::: "memory"); \
    __builtin_amdgcn_s_barrier(); \
    __builtin_amdgcn_sched_barrier(0);

// K-tile, software-pipelined: MFMA(p) uses frags loaded in p-1.
// CAH/CAL: this tile's A-frags (prefetched last tile). NAH/NAL: next tile's,
// prefetched here from buf^1. rb: shared, holds R ni01 (this tile at P1,
// reloaded for next tile at P4top).
#define K_TILE(BUF, CAH,CAL, NAH,NAL, VM1, VM2, DOSTAGE, NEXTK) { \
    const u16* sb = smem + (BUF)*32768; \
    const u16* nb = smem + ((BUF)^1)*32768; \
    u16* _d = dst + (BUF)*32768; \
    const int _ko = (NEXTK)*BK; \
    bf16x8 bh2[2], bl2[2], dh1[2], dl1[2], dh2[2], dl2[2]; \
    /* P1: issue R ni23 (4); MFMA accR ni01 (CAH/CAL/rb from last tile) */ \
    _Pragma("unroll") for(int ni=0;ni<2;++ni){ \
      bh2[ni] = *(const bf16x8*)(sb + 16384 + boff + (2+ni)*512); \
      bl2[ni] = *(const bf16x8*)(sb + 20480 + boff + (2+ni)*512); } \
    PH_PRE("4") \
    _Pragma("unroll") for(int mi=0;mi<4;++mi) \
      _Pragma("unroll") for(int ni=0;ni<2;++ni){ \
        accR[mi][ni] = MFMA16(CAH[mi], rbh[ni], accR[mi][ni]); \
        accR[mi][ni] = MFMA16(CAH[mi], rbl[ni], accR[mi][ni]); \
        accR[mi][ni] = MFMA16(CAL[mi], rbh[ni], accR[mi][ni]); } \
    PH_POST \
    /* P2: stage A(t+2) (A region readers drained P4-prev+P1 lgkm); */ \
    /*     issue D ni01 (4); MFMA accR ni23 (bh2/bl2) */ \
    if (DOSTAGE) { \
      async16(gAh + _ko,            _d);         \
      async16(gAh + 128*IDIM + _ko, _d + 4096);  \
      async16(gAl + _ko,            _d + 8192);  \
      async16(gAl + 128*IDIM + _ko, _d + 12288); } \
    _Pragma("unroll") for(int ni=0;ni<2;++ni){ \
      dh1[ni] = *(const bf16x8*)(sb + 24576 + boff + ni*512); \
      dl1[ni] = *(const bf16x8*)(sb + 28672 + boff + ni*512); } \
    PH_PRE("4") \
    _Pragma("unroll") for(int mi=0;mi<4;++mi) \
      _Pragma("unroll") for(int ni=0;ni<2;++ni){ \
        accR[mi][2+ni] = MFMA16(CAH[mi], bh2[ni], accR[mi][2+ni]); \
        accR[mi][2+ni] = MFMA16(CAH[mi], bl2[ni], accR[mi][2+ni]); \
        accR[mi][2+ni] = MFMA16(CAL[mi], bh2[ni], accR[mi][2+ni]); } \
    PH_POST_VM(VM1) /* F1: A/R of t+1 landed before P3top nb reads */ \
    /* P3: stage R(t+2); issue D ni23 (4) + next-A hi (4 from nb); */ \
    /*     MFMA accD ni01 (dh1/dl1) */ \
    if (DOSTAGE) { \
      async16(gRh + _ko, _d + 16384); \
      async16(gRl + _ko, _d + 20480); } \
    _Pragma("unroll") for(int ni=0;ni<2;++ni){ \
      dh2[ni] = *(const bf16x8*)(sb + 24576 + boff + (2+ni)*512); \
      dl2[ni] = *(const bf16x8*)(sb + 28672 + boff + (2+ni)*512); } \
    _Pragma("unroll") for(int mi=0;mi<4;++mi) \
      NAH[mi] = *(const bf16x8*)(nb + aoff + mi*512); \
    PH_PRE("8") \
    _Pragma("unroll") for(int mi=0;mi<4;++mi) \
      _Pragma("unroll") for(int ni=0;ni<2;++ni){ \
        accD[mi][ni] = MFMA16(CAH[mi], dh1[ni], accD[mi][ni]); \
        accD[mi][ni] = MFMA16(CAH[mi], dl1[ni], accD[mi][ni]); \
        accD[mi][ni] = MFMA16(CAL[mi], dh1[ni], accD[mi][ni]); } \
    PH_POST \
    /* P4: issue next-A lo (4) + next rb (4) from nb; MFMA accD ni23; */ \
    /*     F2 vmcnt; stage D(t+2) after barrier */ \
    _Pragma("unroll") for(int mi=0;mi<4;++mi) \
      NAL[mi] = *(const bf16x8*)(nb + 8192 + aoff + mi*512); \
    _Pragma("unroll") for(int ni=0;ni<2;++ni){ \
      rbh[ni] = *(const bf16x8*)(nb + 16384 + boff + ni*512); \
      rbl[ni] = *(const bf16x8*)(nb + 20480 + boff + ni*512); } \
    PH_PRE("8") \
    _Pragma("unroll") for(int mi=0;mi<4;++mi) \
      _Pragma("unroll") for(int ni=0;ni<2;++ni){ \
        accD[mi][2+ni] = MFMA16(CAH[mi], dh2[ni], accD[mi][2+ni]); \
        accD[mi][2+ni] = MFMA16(CAH[mi], dl2[ni], accD[mi][2+ni]); \
        accD[mi][2+ni] = MFMA16(CAL[mi], dh2[ni], accD[mi][2+ni]); } \
    PH_POST_VM(VM2) /* F2: D of t+1 landed before t+1's P2 reads */ \
    if (DOSTAGE) { \
      async16(gDh + _ko, _d + 24576); \
      async16(gDl + _ko, _d + 28672); } \
    __builtin_amdgcn_sched_barrier(0); \
  }

  STAGE_FULL(0, 0)
  STAGE_FULL(1, 1)
  asm volatile("s_waitcnt vmcnt(8)" ::: "memory");   // tile0 landed
  __builtin_amdgcn_s_barrier();
  __builtin_amdgcn_sched_barrier(0);
  // prologue preload: tile0 A-frags + R ni01 into X/rb (12 reads; drained
  // by first P1's lgkmcnt(4))
  #pragma unroll
  for(int mi=0;mi<4;++mi){
    xah[mi] = *(const bf16x8*)(smem +        aoff + mi*512);
    xal[mi] = *(const bf16x8*)(smem + 8192 + aoff + mi*512);
  }
  #pragma unroll
  for(int ni=0;ni<2;++ni){
    rbh[ni] = *(const bf16x8*)(smem + 16384 + boff + ni*512);
    rbl[ni] = *(const bf16x8*)(smem + 20480 + boff + ni*512);
  }
  __builtin_amdgcn_sched_barrier(0);

  #pragma unroll 1
  for(int t=0; t<NKT-2; t+=2){          // tiles 0..125, staging 2..127
    K_TILE(0, xah,xal, yah,yal, "6","6", 1, t+2)
    K_TILE(1, yah,yal, xah,xal, "6","6", 1, t+3)
  }
  K_TILE(0, xah,xal, yah,yal, "2","0", 0, 0)   // tile 126
  K_TILE(1, yah,yal, xah,xal, "0","0", 0, 0)   // tile 127

#undef K_TILE
#undef PH_PRE
#undef PH_POST
#undef PH_POST_VM
#undef STAGE_FULL
#undef MFMA16

  // epilogue: C/D layout col=lane&15, row=(lane>>4)*4+j (verified)
  const int orow0 = bm*BM + wr*64 + (lane>>4)*4;
  const int ocol0 = bn*BN + wc*64 + (lane & 15);
  #pragma unroll
  for(int ni=0;ni<4;++ni){
    const int col = ocol0 + ni*16;
    const float rb = rad_b[col];
    const float bs = bias[col];
    #pragma unroll
    for(int mi=0;mi<4;++mi){
      const int row = orow0 + mi*16;
      #pragma unroll
      for(int j=0;j<4;++j){
        float s  = accR[mi][ni][j] + rb;
        float sp = (s > 20.f) ? s : log1pf(expf(s));
        out[(size_t)(row+j)*ODIM + col] = accD[mi][ni][j]*sp + bs;
      }
    }
  }
}

extern "C" void kernel_launch(void* const* d_in, const int* in_sizes, int n_in,
                              void* d_out, int out_size, void* d_ws, size_t ws_size,
                              hipStream_t stream){
  (void)in_sizes; (void)n_in; (void)out_size; (void)ws_size;
  const float* inp  = (const float*)d_in[0];  // [8192,4096]
  const float* dirl = (const float*)d_in[1];  // [4096,4096]
  const float* draw = (const float*)d_in[2];  // [4096]
  const float* radw = (const float*)d_in[3];  // [4096,4096]
  const float* radb = (const float*)d_in[4];  // [4096]
  const float* bias = (const float*)d_in[5];  // [4096]
  float* out = (float*)d_out;

  char* ws = (char*)d_ws;
  u16* Ah = (u16*)(ws);
  u16* Al = (u16*)(ws +  67108864L);
  u16* Rh = (u16*)(ws + 134217728L);
  u16* Rl = (u16*)(ws + 167772160L);
  u16* Dh = (u16*)(ws + 201326592L);
  u16* Dl = (u16*)(ws + 234881024L);
  float* scale = (float*)(ws + 268435456L);

  k_scale<<<dim3(ODIM/256), dim3(256), 0, stream>>>(draw, scale);

  const int n4A = BDIM*IDIM/4;
  const int n4W = ODIM*IDIM/4;
  k_split<<<dim3(2048), dim3(256), 0, stream>>>((const f4*)inp,  (u16x4*)Ah, (u16x4*)Al, n4A);
  k_split<<<dim3(2048), dim3(256), 0, stream>>>((const f4*)radw, (u16x4*)Rh, (u16x4*)Rl, n4W);
  k_split_dir<<<dim3(2048), dim3(256), 0, stream>>>((const f4*)dirl, scale, (u16x4*)Dh, (u16x4*)Dl, n4W);

  k_gemm<<<dim3((BDIM/BM)*(ODIM/BN)), dim3(512), 0, stream>>>(
      Ah, Al, Rh, Rl, Dh, Dl, radb, bias, out);
}